// Round 10
// baseline (137.992 us; speedup 1.0000x reference)
//
#include <hip/hip_runtime.h>
#include <hip/hip_bf16.h>
#include <stdint.h>

typedef __bf16 bf16x8 __attribute__((ext_vector_type(8)));
typedef float  f32x4  __attribute__((ext_vector_type(4)));

#define NROWS   8192
#define DIMK    128
#define NGROUPS 2048
#define RECON_N 6422528
#define RECON_BLOCKS 1568            // x256 thr x4 float4 = 6422528 floats
#define GROUP_BLOCKS 512             // x4 groups
#define CONV_BLOCKS  1024            // x256 thr x1 float4 = 1048576 floats
#define PREP_BLOCKS (RECON_BLOCKS + GROUP_BLOCKS + CONV_BLOCKS)   // 3104
#define SIM_BLOCKS   1024            // 64 row-tiles x 16 col-chunks(512)

// workspace layout (float offsets)
#define WS_S      0                  // S[8192], atomically accumulated
#define WS_G      8192
#define WS_E      16384
#define WS_RPART  24576              // 1568
#define WS_DPART  26144              // 512
#define WS_PB     26656              // byte 106624 (16B aligned); bf16 P copy 2MB

__device__ __forceinline__ void async16(const void* g, void* l) {
    __builtin_amdgcn_global_load_lds(
        (const __attribute__((address_space(1))) void*)g,
        (__attribute__((address_space(3))) void*)l, 16, 0, 0);
}

__device__ __forceinline__ unsigned short f2bf(float f) {
    union { __hip_bfloat16 h; unsigned short u; } v;
    v.h = __float2bfloat16(f);
    return v.u;
}

// -------- k2: prep = recon + group + convert (no big LDS, high occupancy) ----
// bx [0,1568): recon   [1568,2080): group   [2080,3104): convert
__global__ __launch_bounds__(256) void prep_kernel(
        const float* __restrict__ Pf,
        const float4* __restrict__ X,
        const float4* __restrict__ Y,
        uint2* __restrict__ Pb,
        float* __restrict__ ws) {
    const int bx = blockIdx.x;
    const int wave = threadIdx.x >> 6, lane = threadIdx.x & 63;

    if (bx < RECON_BLOCKS) {
        __shared__ float red[4];
        int base = bx * 1024 + threadIdx.x;
        float4 a0 = X[base],       b0 = Y[base];
        float4 a1 = X[base + 256], b1 = Y[base + 256];
        float4 a2 = X[base + 512], b2 = Y[base + 512];
        float4 a3 = X[base + 768], b3 = Y[base + 768];
        float s = 0.f, d;
        d = a0.x - b0.x; s += d * d;  d = a0.y - b0.y; s += d * d;
        d = a0.z - b0.z; s += d * d;  d = a0.w - b0.w; s += d * d;
        d = a1.x - b1.x; s += d * d;  d = a1.y - b1.y; s += d * d;
        d = a1.z - b1.z; s += d * d;  d = a1.w - b1.w; s += d * d;
        d = a2.x - b2.x; s += d * d;  d = a2.y - b2.y; s += d * d;
        d = a2.z - b2.z; s += d * d;  d = a2.w - b2.w; s += d * d;
        d = a3.x - b3.x; s += d * d;  d = a3.y - b3.y; s += d * d;
        d = a3.z - b3.z; s += d * d;  d = a3.w - b3.w; s += d * d;
#pragma unroll
        for (int mm = 1; mm < 64; mm <<= 1) s += __shfl_xor(s, mm, 64);
        if (lane == 0) red[wave] = s;
        __syncthreads();
        if (threadIdx.x == 0)
            ws[WS_RPART + bx] = red[0] + red[1] + red[2] + red[3];
    } else if (bx < RECON_BLOCKS + GROUP_BLOCKS) {
        __shared__ float dred[4];
        int gb = bx - RECON_BLOCKS;
        float* G = ws + WS_G;
        float* E = ws + WS_E;
        int g = gb * 4 + wave;
        const float* base = Pf + (size_t)g * 4 * DIMK;
        float v[4][2];
#pragma unroll
        for (int r = 0; r < 4; ++r) {
            v[r][0] = base[r * DIMK + lane];
            v[r][1] = base[r * DIMK + 64 + lane];
        }
        float dmat[4][4];
#pragma unroll
        for (int r = 0; r < 4; ++r)
#pragma unroll
            for (int s2 = r; s2 < 4; ++s2) {
                float p = v[r][0] * v[s2][0] + v[r][1] * v[s2][1];
#pragma unroll
                for (int mm = 1; mm < 64; mm <<= 1) p += __shfl_xor(p, mm, 64);
                dmat[r][s2] = p; dmat[s2][r] = p;
            }
        if (lane == 0) {
            float distp = 0.f;
#pragma unroll
            for (int r = 0; r < 4; ++r)
#pragma unroll
                for (int s2 = r + 1; s2 < 4; ++s2)
                    distp += dmat[r][r] + dmat[s2][s2] - 2.f * dmat[r][s2];
            dred[wave] = distp;
#pragma unroll
            for (int r = 0; r < 4; ++r) {
                float Gs = 0.f, Es = 0.f;
#pragma unroll
                for (int s2 = 0; s2 < 4; ++s2) {
                    float sim = dmat[r][s2] * 10.0f;
                    float e = __expf(sim);
                    Gs += e;
                    if (sim == 1.0f) Es += e;
                }
                G[g * 4 + r] = Gs;
                E[g * 4 + r] = Es;
            }
        }
        __syncthreads();
        if (threadIdx.x == 0)
            ws[WS_DPART + gb] = dred[0] + dred[1] + dred[2] + dred[3];
    } else {
        int cb = bx - (RECON_BLOCKS + GROUP_BLOCKS);
        int idx = cb * 256 + threadIdx.x;       // 262144 float4s
        float4 a = ((const float4*)Pf)[idx];
        uint2 r;
        r.x = (uint32_t)f2bf(a.x) | ((uint32_t)f2bf(a.y) << 16);
        r.y = (uint32_t)f2bf(a.z) | ((uint32_t)f2bf(a.w) << 16);
        Pb[idx] = r;
    }
}

// -------- k3: sim. S[row] += sum_{j in 512-col chunk} exp(P_row . P_j * 10) --
// 1024 blocks = 64 row-tiles x 16 col-chunks. 4 waves: wr=row-half, wc=col-half.
// LDS tile is SWIZZLED: logical 16B chunk (r,q) lives at phys (r, (q+r)&15).
// Staging permutes the async16 *source* (per-lane global addr), keeping the
// wave-uniform LDS scatter; reads become conflict-free (2-way max).
__global__ __launch_bounds__(256, 3) void sim_kernel(
        const unsigned short* __restrict__ Pb,
        float* __restrict__ S) {
    __shared__ unsigned short tile[128 * 128];   // 32 KB
    const int bx = blockIdx.x;
    const int wave = threadIdx.x >> 6, lane = threadIdx.x & 63;
    const int wr = wave >> 1, wc = wave & 1;
    const int rowBase = (bx >> 4) * 128;
    const int colBase = (bx & 15) * 512;
    const int m = lane & 15, kq = lane >> 4;

    // per-lane swizzled source offsets (bytes) for the 8 staging segments
    int srcOff[8];
#pragma unroll
    for (int i = 0; i < 8; ++i) {
        int seg = i * 4 + wave;
        int chunk = seg * 64 + lane;
        int r = chunk >> 4, qp = chunk & 15;
        int q = (qp - r) & 15;
        srcOff[i] = r * 256 + q * 16;
    }

    // stage A tile (rows rowBase..+127), swizzled
    {
        const char* g = (const char*)(Pb + (size_t)rowBase * DIMK);
#pragma unroll
        for (int i = 0; i < 8; ++i) {
            int seg = i * 4 + wave;
            async16(g + srcOff[i], (char*)tile + seg * 1024 + lane * 16);
        }
    }
    __syncthreads();

    // preload A fragments from swizzled tile: A[m][k], row rl, chunk q=kq+kk*4
    bf16x8 Af[4][4];
#pragma unroll
    for (int i = 0; i < 4; ++i) {
        int rl = wr * 64 + i * 16 + m;
#pragma unroll
        for (int kk = 0; kk < 4; ++kk)
            Af[i][kk] = *(const bf16x8*)((const char*)tile + rl * 256 +
                                         (((kq + kk * 4 + rl) & 15) << 4));
    }
    __syncthreads();   // done reading A before overwriting with B

    float rowAcc[4][4];
#pragma unroll
    for (int i = 0; i < 4; ++i)
#pragma unroll
        for (int r = 0; r < 4; ++r) rowAcc[i][r] = 0.f;

    for (int t = 0; t < 4; ++t) {
        {
            const char* g = (const char*)(Pb + (size_t)(colBase + t * 128) * DIMK);
#pragma unroll
            for (int i = 0; i < 8; ++i) {
                int seg = i * 4 + wave;
                async16(g + srcOff[i], (char*)tile + seg * 1024 + lane * 16);
            }
        }
        __syncthreads();

        f32x4 acc[4][4];
#pragma unroll
        for (int i = 0; i < 4; ++i)
#pragma unroll
            for (int j = 0; j < 4; ++j) acc[i][j] = (f32x4){0.f, 0.f, 0.f, 0.f};

#pragma unroll
        for (int kk = 0; kk < 4; ++kk) {
            bf16x8 Bf[4];
#pragma unroll
            for (int j = 0; j < 4; ++j) {
                int rl = wc * 64 + j * 16 + m;
                Bf[j] = *(const bf16x8*)((const char*)tile + rl * 256 +
                                         (((kq + kk * 4 + rl) & 15) << 4));
            }
#pragma unroll
            for (int i = 0; i < 4; ++i)
#pragma unroll
                for (int j = 0; j < 4; ++j)
                    acc[i][j] = __builtin_amdgcn_mfma_f32_16x16x32_bf16(
                        Af[i][kk], Bf[j], acc[i][j], 0, 0, 0);
        }
#pragma unroll
        for (int i = 0; i < 4; ++i)
#pragma unroll
            for (int j = 0; j < 4; ++j)
#pragma unroll
                for (int r = 0; r < 4; ++r)
                    rowAcc[i][r] += __expf(acc[i][j][r] * 10.0f);
        __syncthreads();
    }

    // reduce the 16 lanes sharing a row; each wave adds its col-half partial
#pragma unroll
    for (int i = 0; i < 4; ++i)
#pragma unroll
        for (int r = 0; r < 4; ++r) {
            float sv = rowAcc[i][r];
            sv += __shfl_xor(sv, 1, 64);
            sv += __shfl_xor(sv, 2, 64);
            sv += __shfl_xor(sv, 4, 64);
            sv += __shfl_xor(sv, 8, 64);
            rowAcc[i][r] = sv;
        }
    if ((lane & 15) == 0) {
        int c = lane >> 4;
#pragma unroll
        for (int i = 0; i < 4; ++i)
#pragma unroll
            for (int r = 0; r < 4; ++r)
                atomicAdd(&S[rowBase + wr * 64 + i * 16 + c * 4 + r], rowAcc[i][r]);
    }
}

// -------- k4: finalize — one 1024-thread block, all partial sums + output ----
__global__ __launch_bounds__(1024) void finalize_kernel(const float* __restrict__ ws,
                                                        float* __restrict__ out) {
    __shared__ float redc[16], redr[16], redd[16];
    const float* S = ws + WS_S;
    const float* G = ws + WS_G;
    const float* E = ws + WS_E;

    float c = 0.f;
    for (int r = threadIdx.x; r < NROWS; r += 1024)
        c += __logf(S[r] - E[r]) - __logf(G[r] - E[r]);
    float rs = 0.f;
    for (int i = threadIdx.x; i < RECON_BLOCKS; i += 1024) rs += ws[WS_RPART + i];
    float ds = 0.f;
    for (int i = threadIdx.x; i < GROUP_BLOCKS; i += 1024) ds += ws[WS_DPART + i];

#pragma unroll
    for (int mm = 1; mm < 64; mm <<= 1) {
        c  += __shfl_xor(c,  mm, 64);
        rs += __shfl_xor(rs, mm, 64);
        ds += __shfl_xor(ds, mm, 64);
    }
    int wave = threadIdx.x >> 6, lane = threadIdx.x & 63;
    if (lane == 0) { redc[wave] = c; redr[wave] = rs; redd[wave] = ds; }
    __syncthreads();
    if (threadIdx.x == 0) {
        float cs = 0.f, rss = 0.f, dss = 0.f;
#pragma unroll
        for (int i = 0; i < 16; ++i) { cs += redc[i]; rss += redr[i]; dss += redd[i]; }
        float closs = cs / (float)NROWS;
        float recon = rss / (float)RECON_N;
        float dist  = dss / (float)(NGROUPS * 6 * DIMK);
        out[0] = recon + closs + dist;
        out[1] = closs;
        out[2] = recon;
        out[3] = dist;
    }
}

extern "C" void kernel_launch(void* const* d_in, const int* in_sizes, int n_in,
                              void* d_out, int out_size, void* d_ws, size_t ws_size,
                              hipStream_t stream) {
    const float* P  = (const float*)d_in[0];    // projections 8192x128 fp32
    const float4* X = (const float4*)d_in[1];   // xrecon 8192x784 fp32
    const float4* Y = (const float4*)d_in[2];   // recon_label fp32
    float* out = (float*)d_out;                 // 4 fp32 scalars
    float* w = (float*)d_ws;
    unsigned short* Pb = (unsigned short*)(w + WS_PB);

    hipMemsetAsync(w + WS_S, 0, NROWS * sizeof(float), stream);   // S accumulator
    prep_kernel<<<PREP_BLOCKS, 256, 0, stream>>>(P, X, Y, (uint2*)Pb, w);
    sim_kernel<<<SIM_BLOCKS, 256, 0, stream>>>(Pb, w + WS_S);
    finalize_kernel<<<1, 1024, 0, stream>>>(w, out);
}